// Round 9
// baseline (297.061 us; speedup 1.0000x reference)
//
#include <hip/hip_runtime.h>
#include <hip/hip_bf16.h>
#include <hip/hip_fp16.h>
#include <hip/hip_cooperative_groups.h>

// MeanAggregator: out[n,d] = sum_k mask[n,k]*feat[idx[n,k],d] / max(cnt,1), 0 if cnt==0
// features: [60000,128] f32, idx: [10000,64] i32, mask: [10000,64] i32 (0/1)
//
// R9: single fused cooperative kernel, true-XCC-steered partitioned gather.
//  - R7 proved XCC-locality collapses L2-miss traffic to ~table size; its cost
//    was 26K contended atomics. Here: ONE registration atomic per block,
//    grid.sync, then static per-rank striding (correct for ANY block->XCD
//    distribution; orphan partitions adopted deterministically).
//  - no partition-lists kernel: per-cell in-register compaction via
//    ballot + ds_permute (push crossbar), reading raw idx/mask (L2-resident).
//  - fp16 nontemporal partials; phase B (after grid.sync) combines + divides.

#define N_NEIGH 64
#define D_FEAT 128
#define NPART 8

namespace cg = cooperative_groups;

__global__ __launch_bounds__(256) void fused_agg(
    const float* __restrict__ feat,
    const int* __restrict__ idx,
    const int* __restrict__ mask,
    float* __restrict__ out,
    unsigned long long* __restrict__ partials,  // [NPART][n_nodes][32] u64 (=128 halves)
    unsigned char* __restrict__ cnts8,          // [n_nodes][NPART]
    int* __restrict__ wctr,                     // [NPART], zeroed by host
    int n_nodes, int rpp)
{
    const int tid = threadIdx.x;

    int xcc;
    asm volatile("s_getreg_b32 %0, hwreg(HW_REG_XCC_ID)" : "=s"(xcc));
    xcc &= (NPART - 1);

    __shared__ int s_rank;
    if (tid == 0) s_rank = atomicAdd(&wctr[xcc], 1);
    __syncthreads();
    const int rank = s_rank;

    cg::this_grid().sync();   // all blocks registered

    int C[NPART];
    #pragma unroll
    for (int x = 0; x < NPART; ++x)
        C[x] = __hip_atomic_load(&wctr[x], __ATOMIC_RELAXED, __HIP_MEMORY_SCOPE_AGENT);

    const int w    = tid >> 6;   // wave 0..3
    const int lane = tid & 63;
    const int slot = lane >> 5;  // 2 rows per wave-instruction
    const int d4   = lane & 31;  // 16B chunk of the 512B row

    // ---------------- phase A: partitioned gather ----------------
    for (int p = 0; p < NPART; ++p) {
        // deterministic owner: first XCD at/after p with blocks present
        int owner = -1;
        #pragma unroll
        for (int d = 0; d < NPART; ++d) {
            const int x = (p + d) & (NPART - 1);
            if (owner < 0 && C[x] > 0) owner = x;
        }
        if (owner != xcc) continue;

        const int nb = C[xcc];
        const float* fpart = feat + (long)p * rpp * D_FEAT;

        for (long node = rank + (long)w * nb; node < n_nodes; node += 4L * nb) {
            const int i = idx [node * N_NEIGH + lane];
            const int m = mask[node * N_NEIGH + lane];
            const bool sel = (m != 0) && ((unsigned)(i - p * rpp) < (unsigned)rpp);
            const unsigned long long bal = __ballot(sel);
            const int cnt = (int)__popcll(bal);
            const int pos = (int)__popcll(bal & ((1ull << lane) - 1ull));
            // push my local row id to compacted lane pos (trash lanes -> lane 63,
            // only read when cnt==64, in which case there are no trash lanes)
            const int dst = sel ? (pos << 2) : 252;
            const int rowreg = __builtin_amdgcn_ds_permute(dst, i - p * rpp);

            float4 acc = make_float4(0.f, 0.f, 0.f, 0.f);
            #pragma unroll
            for (int rr = 0; rr < 8; ++rr) {
                const int r = slot + rr * 2;
                if (r < cnt) {
                    const int row = __shfl(rowreg, r);
                    const float4 v = ((const float4*)(fpart + (long)row * D_FEAT))[d4];
                    acc.x += v.x; acc.y += v.y; acc.z += v.z; acc.w += v.w;
                }
            }
            if (cnt > 16) {                       // cnt ~ Binom(64,1/16): rare tail
                for (int r = 16 + slot; r < cnt; r += 2) {
                    const int row = __shfl(rowreg, r);
                    const float4 v = ((const float4*)(fpart + (long)row * D_FEAT))[d4];
                    acc.x += v.x; acc.y += v.y; acc.z += v.z; acc.w += v.w;
                }
            }

            acc.x += __shfl_xor(acc.x, 32);
            acc.y += __shfl_xor(acc.y, 32);
            acc.z += __shfl_xor(acc.z, 32);
            acc.w += __shfl_xor(acc.w, 32);

            if (slot == 0) {
                __half2 h01 = __floats2half2_rn(acc.x, acc.y);
                __half2 h23 = __floats2half2_rn(acc.z, acc.w);
                unsigned long long pk =
                    (unsigned long long)(*reinterpret_cast<unsigned*>(&h01)) |
                    ((unsigned long long)(*reinterpret_cast<unsigned*>(&h23)) << 32);
                __builtin_nontemporal_store(pk,
                    partials + ((long)p * n_nodes + node) * 32 + d4);
            }
            if (lane == 0) cnts8[node * NPART + p] = (unsigned char)cnt;
        }
    }

    cg::this_grid().sync();   // partials + cnts8 visible

    // ---------------- phase B: combine ----------------
    const long groups = ((long)gridDim.x * 256) >> 5;          // 32-thr groups
    const long g0 = ((long)blockIdx.x * 256 + tid) >> 5;
    const int q = tid & 31;

    for (long node = g0; node < n_nodes; node += groups) {
        const unsigned long long c8 =
            *reinterpret_cast<const unsigned long long*>(cnts8 + node * NPART);
        int cnt = 0;
        #pragma unroll
        for (int p = 0; p < NPART; ++p) cnt += (int)((c8 >> (8 * p)) & 0xFFull);

        float4 acc = make_float4(0.f, 0.f, 0.f, 0.f);
        #pragma unroll
        for (int p = 0; p < NPART; ++p) {
            const unsigned long long pk = partials[((long)p * n_nodes + node) * 32 + q];
            unsigned lo = (unsigned)pk;
            unsigned hi = (unsigned)(pk >> 32);
            const float2 v01 = __half22float2(*reinterpret_cast<__half2*>(&lo));
            const float2 v23 = __half22float2(*reinterpret_cast<__half2*>(&hi));
            acc.x += v01.x; acc.y += v01.y; acc.z += v23.x; acc.w += v23.y;
        }
        const float inv = (cnt > 0) ? (1.0f / (float)cnt) : 0.0f;
        acc.x *= inv; acc.y *= inv; acc.z *= inv; acc.w *= inv;
        ((float4*)(out + node * D_FEAT))[q] = acc;
    }
}

// ---------------- Fallback: R4 single-kernel scattered gather --------------
__global__ __launch_bounds__(256) void mean_agg_f32c(
    const float* __restrict__ feat,
    const int* __restrict__ idx,
    const int* __restrict__ mask,
    float* __restrict__ out,
    int n_nodes)
{
    const int node = blockIdx.x;

    __shared__ int s_cidx[N_NEIGH];
    __shared__ int s_cnt;
    __shared__ float4 s_part[4][32];

    const int tid = threadIdx.x;

    if (tid < 64) {
        const int i = idx[(long)node * N_NEIGH + tid];
        const int m = mask[(long)node * N_NEIGH + tid];
        const unsigned long long bal = __ballot(m != 0);
        const int pos = __popcll(bal & ((1ull << tid) - 1ull));
        if (m) s_cidx[pos] = i;
        if (tid == 0) s_cnt = (int)__popcll(bal);
    }
    __syncthreads();

    const int cnt = s_cnt;
    const int slot = tid >> 5;
    const int d4   = tid & 31;

    float4 acc = make_float4(0.f, 0.f, 0.f, 0.f);
    #pragma unroll
    for (int rr = 0; rr < 8; ++rr) {
        const int r = slot + rr * 8;
        if (r < cnt) {
            const float4 v = ((const float4*)(feat + (long)s_cidx[r] * D_FEAT))[d4];
            acc.x += v.x; acc.y += v.y; acc.z += v.z; acc.w += v.w;
        }
    }
    acc.x += __shfl_xor(acc.x, 32);
    acc.y += __shfl_xor(acc.y, 32);
    acc.z += __shfl_xor(acc.z, 32);
    acc.w += __shfl_xor(acc.w, 32);

    const int wv = tid >> 6;
    if ((tid & 63) < 32) s_part[wv][d4] = acc;
    __syncthreads();

    if (tid < 32) {
        const float4 p0 = s_part[0][tid];
        const float4 p1 = s_part[1][tid];
        const float4 p2 = s_part[2][tid];
        const float4 p3 = s_part[3][tid];
        float4 t;
        t.x = (p0.x + p1.x) + (p2.x + p3.x);
        t.y = (p0.y + p1.y) + (p2.y + p3.y);
        t.z = (p0.z + p1.z) + (p2.z + p3.z);
        t.w = (p0.w + p1.w) + (p2.w + p3.w);
        const float inv = (cnt > 0) ? (1.0f / (float)cnt) : 0.0f;
        t.x *= inv; t.y *= inv; t.z *= inv; t.w *= inv;
        ((float4*)(out + (long)node * D_FEAT))[tid] = t;
    }
}

extern "C" void kernel_launch(void* const* d_in, const int* in_sizes, int n_in,
                              void* d_out, int out_size, void* d_ws, size_t ws_size,
                              hipStream_t stream) {
    const float* feat = (const float*)d_in[0];
    const int*   idx  = (const int*)d_in[1];
    const int*   mask = (const int*)d_in[2];
    float*       out  = (float*)d_out;

    int n_nodes = in_sizes[1] / N_NEIGH;              // 10000
    const int n_src = in_sizes[0] / D_FEAT;           // 60000
    int rpp = (n_src + NPART - 1) / NPART;            // 7500

    const size_t sz_part  = (size_t)NPART * n_nodes * 32 * sizeof(unsigned long long);
    const size_t off_c8   = (sz_part + 255) & ~(size_t)255;
    const size_t sz_c8    = (size_t)n_nodes * NPART;
    const size_t off_wctr = (off_c8 + sz_c8 + 255) & ~(size_t)255;
    const size_t need     = off_wctr + NPART * sizeof(int);

    int maxb = 0;
    hipError_t oe = hipOccupancyMaxActiveBlocksPerMultiprocessor(&maxb, fused_agg, 256, 0);
    int ncu = 256;
    {
        hipDeviceProp_t prop;
        int dev = 0;
        if (hipGetDevice(&dev) == hipSuccess &&
            hipGetDeviceProperties(&prop, dev) == hipSuccess)
            ncu = prop.multiProcessorCount;
    }

    if (ws_size >= need && oe == hipSuccess && maxb > 0) {
        unsigned long long* partials = (unsigned long long*)d_ws;
        unsigned char* cnts8 = (unsigned char*)d_ws + off_c8;
        int* wctr = (int*)((char*)d_ws + off_wctr);

        int G = maxb * ncu;
        if (G > 2048) G = 2048;

        hipMemsetAsync(wctr, 0, NPART * sizeof(int), stream);
        void* args[] = {(void*)&feat, (void*)&idx, (void*)&mask, (void*)&out,
                        (void*)&partials, (void*)&cnts8, (void*)&wctr,
                        (void*)&n_nodes, (void*)&rpp};
        hipLaunchCooperativeKernel(fused_agg, dim3(G), dim3(256), args, 0, stream);
    } else {
        mean_agg_f32c<<<n_nodes, 256, 0, stream>>>(feat, idx, mask, out, n_nodes);
    }
}

// Round 10
// 32.649 us; speedup vs baseline: 9.0985x; 9.0985x over previous
//
#include <hip/hip_runtime.h>
#include <hip/hip_bf16.h>
#include <hip/hip_fp16.h>

// MeanAggregator: out[n,d] = sum_k mask[n,k]*feat[idx[n,k],d] / max(cnt,1), 0 if cnt==0
// features: [60000,128] f32, idx: [10000,64] i32, mask: [10000,64] i32 (0/1)
//
// R10: co-resident static XCD-partitioned gather.
//  - R7 proved XCC-locality collapses L2-miss traffic (FETCH 75->23.6 MB);
//    R7/R9 showed contended same-line atomics cost ~12ns each serialized
//    (26K ops = 305us) -> any dynamic scheduling is dead.
//  - Here: grid of EXACTLY 2048 blocks (8/CU x 256 CU, 24 VGPR, 0 LDS) ->
//    single dispatch wave, no retire-drift; p = bid&7 rides the round-robin
//    block->XCD dispatch (m157 swizzle evidence). Zero scheduling ops.
//  - No K1: in-register ballot + ds_permute compaction from raw idx/mask.
//  - fp16 nontemporal partials (stay out of L2); small combine kernel.

#define N_NEIGH 64
#define D_FEAT 128
#define NPART 8

// ---------------- K2: static co-resident partitioned gather ----------------
__global__ __launch_bounds__(256) void gather_xcd(
    const float* __restrict__ feat,
    const int* __restrict__ idx,
    const int* __restrict__ mask,
    unsigned long long* __restrict__ partials,  // [NPART][n_nodes][32] u64 (=128 halves)
    unsigned char* __restrict__ cnts8,          // [n_nodes][NPART]
    int n_nodes, int rpp)
{
    const int p     = blockIdx.x & (NPART - 1);  // partition; round-robin -> XCD
    const int brank = blockIdx.x >> 3;           // 0..255 within partition
    const int tid  = threadIdx.x;
    const int w    = tid >> 6;   // wave 0..3
    const int lane = tid & 63;
    const int slot = lane >> 5;  // 2 rows per wave-instruction
    const int d4   = lane & 31;  // 16B chunk of the 512B row

    const float* fpart = feat + (long)p * rpp * D_FEAT;

    for (int node = brank * 4 + w; node < n_nodes; node += 1024) {
        const long nb = (long)node * N_NEIGH + lane;
        const int i = idx[nb];
        const int m = mask[nb];
        const int loc = i - p * rpp;
        const bool sel = (m != 0) && ((unsigned)loc < (unsigned)rpp);
        const unsigned long long bal = __ballot(sel);
        const int cnt = (int)__popcll(bal);
        const int pos = (int)__popcll(bal & ((1ull << lane) - 1ull));
        // push my local row id to compacted lane pos; trash lanes -> lane 63
        // (lane 63 is only read when cnt==64, i.e. no trash lanes)
        const int dst = sel ? (pos << 2) : 252;
        const int rowreg = __builtin_amdgcn_ds_permute(dst, loc);

        float4 acc = make_float4(0.f, 0.f, 0.f, 0.f);
        #pragma unroll
        for (int rr = 0; rr < 8; ++rr) {
            const int r = slot + rr * 2;
            if (r < cnt) {
                const int row = __shfl(rowreg, r);
                const float4 v = ((const float4*)(fpart + (long)row * D_FEAT))[d4];
                acc.x += v.x; acc.y += v.y; acc.z += v.z; acc.w += v.w;
            }
        }
        if (cnt > 16) {                    // cnt ~ Binom(64,1/16): very rare tail
            for (int r = 16 + slot; r < cnt; r += 2) {
                const int row = __shfl(rowreg, r);
                const float4 v = ((const float4*)(fpart + (long)row * D_FEAT))[d4];
                acc.x += v.x; acc.y += v.y; acc.z += v.z; acc.w += v.w;
            }
        }

        acc.x += __shfl_xor(acc.x, 32);
        acc.y += __shfl_xor(acc.y, 32);
        acc.z += __shfl_xor(acc.z, 32);
        acc.w += __shfl_xor(acc.w, 32);

        if (slot == 0) {
            __half2 h01 = __floats2half2_rn(acc.x, acc.y);
            __half2 h23 = __floats2half2_rn(acc.z, acc.w);
            unsigned long long pk =
                (unsigned long long)(*reinterpret_cast<unsigned*>(&h01)) |
                ((unsigned long long)(*reinterpret_cast<unsigned*>(&h23)) << 32);
            __builtin_nontemporal_store(pk,
                partials + ((long)p * n_nodes + node) * 32 + d4);
        }
        if (lane == 0) cnts8[(long)node * NPART + p] = (unsigned char)cnt;
    }
}

// ---------------- K3: combine partials ----------------
__global__ __launch_bounds__(256) void combine_kernel(
    const unsigned long long* __restrict__ partials,  // [NPART][n_nodes][32] u64
    const unsigned char* __restrict__ cnts8,          // [n_nodes][NPART]
    float* __restrict__ out, int n_nodes)
{
    const int tid = threadIdx.x;
    const int node = blockIdx.x * 8 + (tid >> 5);  // 32 threads per node
    const int q = tid & 31;                        // which u64 (4 halves)
    if (node >= n_nodes) return;

    const unsigned long long c8 =
        *reinterpret_cast<const unsigned long long*>(cnts8 + (long)node * NPART);
    int cnt = 0;
    #pragma unroll
    for (int p = 0; p < NPART; ++p) cnt += (int)((c8 >> (8 * p)) & 0xFFull);

    float4 acc = make_float4(0.f, 0.f, 0.f, 0.f);
    #pragma unroll
    for (int p = 0; p < NPART; ++p) {
        const unsigned long long pk = partials[((long)p * n_nodes + node) * 32 + q];
        unsigned lo = (unsigned)pk;
        unsigned hi = (unsigned)(pk >> 32);
        const float2 v01 = __half22float2(*reinterpret_cast<__half2*>(&lo));
        const float2 v23 = __half22float2(*reinterpret_cast<__half2*>(&hi));
        acc.x += v01.x; acc.y += v01.y; acc.z += v23.x; acc.w += v23.y;
    }
    const float inv = (cnt > 0) ? (1.0f / (float)cnt) : 0.0f;
    acc.x *= inv; acc.y *= inv; acc.z *= inv; acc.w *= inv;
    ((float4*)(out + (long)node * D_FEAT))[q] = acc;
}

// ---------------- Fallback (ws too small): R4 single-kernel gather --------
__global__ __launch_bounds__(256) void mean_agg_f32c(
    const float* __restrict__ feat,
    const int* __restrict__ idx,
    const int* __restrict__ mask,
    float* __restrict__ out,
    int n_nodes)
{
    const int node = blockIdx.x;

    __shared__ int s_cidx[N_NEIGH];
    __shared__ int s_cnt;
    __shared__ float4 s_part[4][32];

    const int tid = threadIdx.x;

    if (tid < 64) {
        const int i = idx[(long)node * N_NEIGH + tid];
        const int m = mask[(long)node * N_NEIGH + tid];
        const unsigned long long bal = __ballot(m != 0);
        const int pos = __popcll(bal & ((1ull << tid) - 1ull));
        if (m) s_cidx[pos] = i;
        if (tid == 0) s_cnt = (int)__popcll(bal);
    }
    __syncthreads();

    const int cnt = s_cnt;
    const int slot = tid >> 5;
    const int d4   = tid & 31;

    float4 acc = make_float4(0.f, 0.f, 0.f, 0.f);
    #pragma unroll
    for (int rr = 0; rr < 8; ++rr) {
        const int r = slot + rr * 8;
        if (r < cnt) {
            const float4 v = ((const float4*)(feat + (long)s_cidx[r] * D_FEAT))[d4];
            acc.x += v.x; acc.y += v.y; acc.z += v.z; acc.w += v.w;
        }
    }
    acc.x += __shfl_xor(acc.x, 32);
    acc.y += __shfl_xor(acc.y, 32);
    acc.z += __shfl_xor(acc.z, 32);
    acc.w += __shfl_xor(acc.w, 32);

    const int wv = tid >> 6;
    if ((tid & 63) < 32) s_part[wv][d4] = acc;
    __syncthreads();

    if (tid < 32) {
        const float4 p0 = s_part[0][tid];
        const float4 p1 = s_part[1][tid];
        const float4 p2 = s_part[2][tid];
        const float4 p3 = s_part[3][tid];
        float4 t;
        t.x = (p0.x + p1.x) + (p2.x + p3.x);
        t.y = (p0.y + p1.y) + (p2.y + p3.y);
        t.z = (p0.z + p1.z) + (p2.z + p3.z);
        t.w = (p0.w + p1.w) + (p2.w + p3.w);
        const float inv = (cnt > 0) ? (1.0f / (float)cnt) : 0.0f;
        t.x *= inv; t.y *= inv; t.z *= inv; t.w *= inv;
        ((float4*)(out + (long)node * D_FEAT))[tid] = t;
    }
}

extern "C" void kernel_launch(void* const* d_in, const int* in_sizes, int n_in,
                              void* d_out, int out_size, void* d_ws, size_t ws_size,
                              hipStream_t stream) {
    const float* feat = (const float*)d_in[0];
    const int*   idx  = (const int*)d_in[1];
    const int*   mask = (const int*)d_in[2];
    float*       out  = (float*)d_out;

    const int n_nodes = in_sizes[1] / N_NEIGH;        // 10000
    const int n_src   = in_sizes[0] / D_FEAT;         // 60000
    const int rpp     = (n_src + NPART - 1) / NPART;  // 7500

    const size_t sz_part = (size_t)NPART * n_nodes * 32 * sizeof(unsigned long long);
    const size_t off_c8  = (sz_part + 255) & ~(size_t)255;
    const size_t need    = off_c8 + (size_t)n_nodes * NPART;

    if (ws_size >= need) {
        unsigned long long* partials = (unsigned long long*)d_ws;
        unsigned char* cnts8 = (unsigned char*)d_ws + off_c8;

        gather_xcd<<<2048, 256, 0, stream>>>(feat, idx, mask, partials, cnts8, n_nodes, rpp);
        combine_kernel<<<(n_nodes + 7) / 8, 256, 0, stream>>>(partials, cnts8, out, n_nodes);
    } else {
        mean_agg_f32c<<<n_nodes, 256, 0, stream>>>(feat, idx, mask, out, n_nodes);
    }
}